// Round 7
// baseline (47.144 us; speedup 1.0000x reference)
//
#include <hip/hip_runtime.h>
#include <hip/hip_bf16.h>

#define NVOX 4096
#define C    128
#define HID  512
#define EPSF 1e-6f

typedef __attribute__((ext_vector_type(8))) short bf16x8;
typedef __attribute__((ext_vector_type(4))) float f32x4;

__device__ __forceinline__ short f2bs(float f) {
    __hip_bfloat16 h = __float2bfloat16(f);
    short s; __builtin_memcpy(&s, &h, 2); return s;
}
__device__ __forceinline__ float bs2f(unsigned short u) {
    return __uint_as_float(((unsigned)u) << 16);
}

// A-frag from swizzled LDS tile hs[16][128] (bf16 shorts, col ^ ((row&7)<<3))
__device__ __forceinline__ bf16x8 lda(const short* hs, int lane, int ks) {
    int r = lane & 15, g = lane >> 4;
    int col = (ks * 32 + g * 8) ^ ((r & 7) << 3);
    return *(const bf16x8*)(hs + r * 128 + col);
}

// ---------- weight prep: convert fp32 weights -> bf16 fragment-order ----------
__global__ __launch_bounds__(256) void k_prep(
    const float* __restrict__ wq, const float* __restrict__ wk,
    const float* __restrict__ wv, const float* __restrict__ wo,
    const float* __restrict__ gw, const float* __restrict__ uw,
    const float* __restrict__ dw, short* __restrict__ wsw)
{
    int id = blockIdx.x * 256 + threadIdx.x;   // 262144 total
    const float* src; int base, k, c, N, K;
    if (id < 65536) {
        int m = id >> 14, loc = id & 16383;
        src = (m == 0) ? wq : (m == 1) ? wk : (m == 2) ? wv : wo;
        base = m << 14; N = 128; K = 128;
        k = loc >> 7; c = loc & 127;
    } else {
        int l2 = id - 65536, m = l2 >> 16, loc = l2 & 65535;
        if (m == 0)      { src = gw; base = 65536;  N = 512; K = 128; }
        else if (m == 1) { src = uw; base = 131072; N = 512; K = 128; }
        else             { src = dw; base = 196608; N = 128; K = 512; }
        k = (N == 512) ? (loc >> 9) : (loc >> 7);
        c = (N == 512) ? (loc & 511) : (loc & 127);
    }
    int KS = K >> 5;
    int ct = c >> 4, ks = k >> 5, lane = ((k >> 3) & 3) * 16 + (c & 15), j = k & 7;
    wsw[base + (((ct * KS + ks) * 64 + lane) << 3) + j] = f2bs(src[k * N + c]);
}

// ---------- K1: rmsnorm(x)*n1 -> q(f32), k(bf16), v(bf16); 512 thr, 8 waves ----------
__global__ __launch_bounds__(512) void k_qkv(
    const float* __restrict__ x, const float* __restrict__ n1,
    const short* __restrict__ wsw,
    float* __restrict__ q, short* __restrict__ kbf, short* __restrict__ vbf)
{
    __shared__ float xs[16][128];
    __shared__ short hs[2048];
    __shared__ float red[16][8];
    __shared__ float scl[16];
    const int r0 = blockIdx.x * 16, t = threadIdx.x;

    for (int vi = t; vi < 512; vi += 512) {
        int r = vi >> 5, jc = (vi & 31) << 2;
        *(float4*)&xs[r][jc] = *(const float4*)&x[(size_t)(r0 + r) * 128 + jc];
    }
    __syncthreads();
    if (t < 128) {
        int r = t >> 3, seg = t & 7; float s = 0.f;
        #pragma unroll
        for (int i = 0; i < 16; i++) { float xv = xs[r][seg * 16 + i]; s = fmaf(xv, xv, s); }
        red[r][seg] = s;
    }
    __syncthreads();
    if (t < 16) {
        float s = 0.f;
        #pragma unroll
        for (int i = 0; i < 8; i++) s += red[t][i];
        scl[t] = rsqrtf(s * (1.0f / 128.0f) + EPSF);
    }
    __syncthreads();
    for (int vi = t; vi < 2048; vi += 512) {
        int r = vi >> 7, c = vi & 127;
        hs[r * 128 + (c ^ ((r & 7) << 3))] = f2bs(xs[r][c] * scl[r] * n1[c]);
    }
    __syncthreads();

    const int w = t >> 6, lane = t & 63;
    bf16x8 af[4];
    #pragma unroll
    for (int ks = 0; ks < 4; ks++) af[ks] = lda(hs, lane, ks);

    const int rb = (lane >> 4) * 4, cl = lane & 15;
    // 24 col-tiles across [q|k|v]; wave w does tiles 3w..3w+2
    #pragma unroll
    for (int i = 0; i < 3; i++) {
        int gt = w * 3 + i;
        int m = gt >> 3, ct = gt & 7;
        const short* wb = wsw + (m << 14);
        f32x4 a0 = {0.f,0.f,0.f,0.f};
        #pragma unroll
        for (int ks = 0; ks < 4; ks++) {
            bf16x8 b0 = *(const bf16x8*)(wb + (((ct * 4 + ks) * 64 + lane) << 3));
            a0 = __builtin_amdgcn_mfma_f32_16x16x32_bf16(af[ks], b0, a0, 0, 0, 0);
        }
        if (m == 0) {
            #pragma unroll
            for (int j = 0; j < 4; j++)
                q[(size_t)(r0 + rb + j) * 128 + ct * 16 + cl] = a0[j];
        } else {
            short* outp = (m == 1) ? kbf : vbf;
            #pragma unroll
            for (int j = 0; j < 4; j++)
                outp[(size_t)(r0 + rb + j) * 128 + ct * 16 + cl] = f2bs(a0[j]);
        }
    }
}

// ---------- K2: brick-tiled local attention; 512 thr, 16 lanes/query ----------
__global__ __launch_bounds__(512) void k_attn(
    const float* __restrict__ q, const short* __restrict__ kbf,
    const short* __restrict__ vbf, short* __restrict__ obf)
{
    __shared__ short K_lds[384 * 40];
    __shared__ short V_lds[384 * 40];
    __shared__ int tab[125];

    const int b = blockIdx.x, head = blockIdx.y, t = threadIdx.x;
    const int ow = (b & 3) * 4, oh = ((b >> 2) & 3) * 4, od = (b >> 4) * 2;

    if (t < 125) {
        int dd = t / 25, rem = t % 25;
        tab[t] = dd | ((rem / 5) << 4) | ((rem % 5) << 8);
    }
    if (t < 384) {
        int row = t;
        int lw = row & 7, lh = (row >> 3) & 7, ld = row >> 6;
        int gd = od - 2 + ld, gh = oh - 2 + lh, gw = ow - 2 + lw;
        uint4 kc[4], vc[4];
        if (((unsigned)gd < 16u) && ((unsigned)gh < 16u) && ((unsigned)gw < 16u)) {
            size_t off = ((size_t)(((gd << 4) | gh) << 4 | gw)) * 128 + head * 32;
            #pragma unroll
            for (int c2 = 0; c2 < 4; c2++) {
                kc[c2] = *(const uint4*)(kbf + off + c2 * 8);
                vc[c2] = *(const uint4*)(vbf + off + c2 * 8);
            }
        } else {
            #pragma unroll
            for (int c2 = 0; c2 < 4; c2++) { kc[c2] = (uint4){0,0,0,0}; vc[c2] = (uint4){0,0,0,0}; }
        }
        #pragma unroll
        for (int c2 = 0; c2 < 4; c2++) {
            *(uint4*)&K_lds[row * 40 + c2 * 8] = kc[c2];
            *(uint4*)&V_lds[row * 40 + c2 * 8] = vc[c2];
        }
    }
    __syncthreads();

    const int qi = t >> 4, qt = t & 15;          // 32 queries x 16 lanes
    const int qw_ = qi & 3, qh_ = (qi >> 2) & 3, qd_ = qi >> 4;
    const int gqd = od + qd_, gqh = oh + qh_, gqw = ow + qw_;
    const int gvox = (((gqd << 4) | gqh) << 4) | gqw;
    const int base = (qd_ + 2) * 64 + (qh_ + 2) * 8 + (qw_ + 2);

    float qreg[32];
    {
        const float isq = 0.17677669529663687f;
        const float* qp = q + (size_t)gvox * 128 + head * 32;
        #pragma unroll
        for (int c2 = 0; c2 < 8; c2++) {
            float4 f = *(const float4*)(qp + c2 * 4);
            qreg[c2 * 4 + 0] = f.x * isq; qreg[c2 * 4 + 1] = f.y * isq;
            qreg[c2 * 4 + 2] = f.z * isq; qreg[c2 * 4 + 3] = f.w * isq;
        }
    }

    float sc[8]; int hid[8];
    float m = -1e30f;
    const int kk0 = qt * 8;
    #pragma unroll
    for (int i = 0; i < 8; i++) {
        int kk = kk0 + i;
        float s = -1e30f; int h = 0;
        if (kk < 125) {
            int tt = tab[kk];
            int dd = (tt & 15) - 2, dh = ((tt >> 4) & 15) - 2, dw = (tt >> 8) - 2;
            if (((unsigned)(gqd + dd) < 16u) & ((unsigned)(gqh + dh) < 16u) & ((unsigned)(gqw + dw) < 16u)) {
                h = base + dd * 64 + dh * 8 + dw;
                float acc = 0.f;
                #pragma unroll
                for (int c2 = 0; c2 < 4; c2++) {
                    uint4 raw = *(const uint4*)&K_lds[h * 40 + c2 * 8];
                    const unsigned short* u = (const unsigned short*)&raw;
                    #pragma unroll
                    for (int j = 0; j < 8; j++) acc = fmaf(qreg[c2 * 8 + j], bs2f(u[j]), acc);
                }
                s = acc;
            }
        }
        sc[i] = s; hid[i] = h;
        m = fmaxf(m, s);
    }
    m = fmaxf(m, __shfl_xor(m, 1));
    m = fmaxf(m, __shfl_xor(m, 2));
    m = fmaxf(m, __shfl_xor(m, 4));
    m = fmaxf(m, __shfl_xor(m, 8));
    float ssum = 0.f;
    #pragma unroll
    for (int i = 0; i < 8; i++) {
        float p = (sc[i] > -1e29f) ? __expf(sc[i] - m) : 0.f;
        sc[i] = p; ssum += p;
    }
    ssum += __shfl_xor(ssum, 1);
    ssum += __shfl_xor(ssum, 2);
    ssum += __shfl_xor(ssum, 4);
    ssum += __shfl_xor(ssum, 8);
    const float inv = 1.0f / ssum;

    float acc[32];
    #pragma unroll
    for (int c2 = 0; c2 < 32; c2++) acc[c2] = 0.f;
    #pragma unroll
    for (int i = 0; i < 8; i++) {
        float p = sc[i]; int h = hid[i];
        #pragma unroll
        for (int c2 = 0; c2 < 4; c2++) {
            uint4 raw = *(const uint4*)&V_lds[h * 40 + c2 * 8];
            const unsigned short* u = (const unsigned short*)&raw;
            #pragma unroll
            for (int j = 0; j < 8; j++) acc[c2 * 8 + j] = fmaf(p, bs2f(u[j]), acc[c2 * 8 + j]);
        }
    }
    #pragma unroll
    for (int c2 = 0; c2 < 32; c2++) {
        acc[c2] += __shfl_xor(acc[c2], 1);
        acc[c2] += __shfl_xor(acc[c2], 2);
        acc[c2] += __shfl_xor(acc[c2], 4);
        acc[c2] += __shfl_xor(acc[c2], 8);
    }
    // each of the 16 lanes writes 2 channels (4 B)
    short o0 = f2bs(acc[qt * 2] * inv);
    short o1 = f2bs(acc[qt * 2 + 1] * inv);
    unsigned pk = (unsigned)(unsigned short)o0 | ((unsigned)(unsigned short)o1 << 16);
    *(unsigned*)&obf[(size_t)gvox * 128 + head * 32 + qt * 2] = pk;
}

// ---------- K3: fused post-chain (attnout + ffn1 + ffn2); 512 thr, 8 waves ----------
__global__ __launch_bounds__(512) void k_post(
    const short* __restrict__ obf, const short* __restrict__ wsw,
    const float* __restrict__ anw, const float* __restrict__ x,
    const float* __restrict__ n2w, float* __restrict__ out)
{
    __shared__ float ybuf[16][132];
    __shared__ float xres[16][128];
    __shared__ short hs[2048];
    __shared__ short gu[16 * 512];
    __shared__ float red[16][8];
    __shared__ float scl[16];

    const int r0 = blockIdx.x * 16, t = threadIdx.x;
    const int w = t >> 6, lane = t & 63;
    const int ar = lane & 15, ag_ = lane >> 4;

    // phase 1: y = o @ wo  (8 waves x 16-col tile each)
    {
        const short* wb = wsw + (3 << 14);
        f32x4 a0 = {0.f,0.f,0.f,0.f};
        #pragma unroll
        for (int ks = 0; ks < 4; ks++) {
            bf16x8 a = *(const bf16x8*)(obf + (size_t)(r0 + ar) * 128 + ks * 32 + ag_ * 8);
            bf16x8 b0 = *(const bf16x8*)(wb + (((w * 4 + ks) * 64 + lane) << 3));
            a0 = __builtin_amdgcn_mfma_f32_16x16x32_bf16(a, b0, a0, 0, 0, 0);
        }
        #pragma unroll
        for (int i = 0; i < 4; i++)
            ybuf[ag_ * 4 + i][w * 16 + ar] = a0[i];
    }
    __syncthreads();

    // phase 2: xres = x + rmsnorm(y)*anw
    if (t < 128) {
        int r = t >> 3, seg = t & 7; float s = 0.f;
        #pragma unroll
        for (int i = 0; i < 16; i++) { float yv = ybuf[r][seg * 16 + i]; s = fmaf(yv, yv, s); }
        red[r][seg] = s;
    }
    __syncthreads();
    if (t < 16) {
        float s = 0.f;
        #pragma unroll
        for (int i = 0; i < 8; i++) s += red[t][i];
        scl[t] = rsqrtf(s * (1.0f / 128.0f) + EPSF);
    }
    __syncthreads();
    for (int vi = t; vi < 512; vi += 512) {
        int r = vi >> 5, jc = (vi & 31) << 2;
        float4 xv = *(const float4*)&x[(size_t)(r0 + r) * 128 + jc];
        float4 aw = *(const float4*)&anw[jc];
        float sc2 = scl[r];
        float4 o;
        o.x = xv.x + ybuf[r][jc + 0] * sc2 * aw.x;
        o.y = xv.y + ybuf[r][jc + 1] * sc2 * aw.y;
        o.z = xv.z + ybuf[r][jc + 2] * sc2 * aw.z;
        o.w = xv.w + ybuf[r][jc + 3] * sc2 * aw.w;
        *(float4*)&xres[r][jc] = o;
    }
    __syncthreads();

    // phase 3: h2 = rmsnorm(xres)*n2w -> hs (swizzled bf16)
    if (t < 128) {
        int r = t >> 3, seg = t & 7; float s = 0.f;
        #pragma unroll
        for (int i = 0; i < 16; i++) { float xv = xres[r][seg * 16 + i]; s = fmaf(xv, xv, s); }
        red[r][seg] = s;
    }
    __syncthreads();
    if (t < 16) {
        float s = 0.f;
        #pragma unroll
        for (int i = 0; i < 8; i++) s += red[t][i];
        scl[t] = rsqrtf(s * (1.0f / 128.0f) + EPSF);
    }
    __syncthreads();
    for (int vi = t; vi < 2048; vi += 512) {
        int r = vi >> 7, c = vi & 127;
        hs[r * 128 + (c ^ ((r & 7) << 3))] = f2bs(xres[r][c] * scl[r] * n2w[c]);
    }
    __syncthreads();

    // phase 4: gu = silu(h2@gw)*(h2@uw)   (8 waves x 4 col-tiles each)
    {
        const short* gwb = wsw + 65536;
        const short* uwb = wsw + 131072;
        bf16x8 af[4];
        #pragma unroll
        for (int ks = 0; ks < 4; ks++) af[ks] = lda(hs, lane, ks);
        f32x4 ag[4], au[4];
        #pragma unroll
        for (int i = 0; i < 4; i++) { ag[i] = (f32x4){0.f,0.f,0.f,0.f}; au[i] = (f32x4){0.f,0.f,0.f,0.f}; }
        #pragma unroll
        for (int ks = 0; ks < 4; ks++) {
            #pragma unroll
            for (int i = 0; i < 4; i++) {
                int ct = w * 4 + i;
                bf16x8 bg = *(const bf16x8*)(gwb + (((ct * 4 + ks) * 64 + lane) << 3));
                bf16x8 bu = *(const bf16x8*)(uwb + (((ct * 4 + ks) * 64 + lane) << 3));
                ag[i] = __builtin_amdgcn_mfma_f32_16x16x32_bf16(af[ks], bg, ag[i], 0, 0, 0);
                au[i] = __builtin_amdgcn_mfma_f32_16x16x32_bf16(af[ks], bu, au[i], 0, 0, 0);
            }
        }
        #pragma unroll
        for (int i = 0; i < 4; i++) {
            int col = (w * 4 + i) * 16 + ar;
            #pragma unroll
            for (int j = 0; j < 4; j++) {
                int row = ag_ * 4 + j;
                float g = ag[i][j], u = au[i][j];
                float sg = g / (1.0f + __expf(-g));
                gu[row * 512 + (col ^ ((row & 7) << 3))] = f2bs(sg * u);
            }
        }
    }
    __syncthreads();

    // phase 5: out = xres + gu @ dw  (8 waves x 16-col tile, K=512)
    {
        const short* db = wsw + 196608;
        f32x4 a0 = {0.f,0.f,0.f,0.f};
        #pragma unroll
        for (int ks = 0; ks < 16; ks++) {
            int col = (ks * 32 + ag_ * 8) ^ ((ar & 7) << 3);
            bf16x8 a = *(const bf16x8*)(gu + ar * 512 + col);
            bf16x8 b0 = *(const bf16x8*)(db + (((w * 16 + ks) * 64 + lane) << 3));
            a0 = __builtin_amdgcn_mfma_f32_16x16x32_bf16(a, b0, a0, 0, 0, 0);
        }
        #pragma unroll
        for (int i = 0; i < 4; i++) {
            int row = ag_ * 4 + i;
            size_t i0 = (size_t)(r0 + row) * 128 + w * 16 + ar;
            out[i0] = xres[row][w * 16 + ar] + a0[i];
        }
    }
}

extern "C" void kernel_launch(void* const* d_in, const int* in_sizes, int n_in,
                              void* d_out, int out_size, void* d_ws, size_t ws_size,
                              hipStream_t stream)
{
    const float* x   = (const float*)d_in[0];
    const float* n1  = (const float*)d_in[1];
    const float* anw = (const float*)d_in[2];
    const float* n2  = (const float*)d_in[3];
    const float* wq  = (const float*)d_in[4];
    const float* wk  = (const float*)d_in[5];
    const float* wv  = (const float*)d_in[6];
    const float* wo  = (const float*)d_in[7];
    const float* gw  = (const float*)d_in[8];
    const float* uw  = (const float*)d_in[9];
    const float* dw  = (const float*)d_in[10];
    float* out = (float*)d_out;

    float* ws = (float*)d_ws;
    float* q    = ws;                         // 524288 f
    short* kbf  = (short*)(ws + 524288);
    short* vbf  = (short*)(ws + 786432);
    short* obf  = (short*)(ws + 1048576);
    short* wsw  = (short*)(ws + 1310720);

    k_prep<<<1024, 256, 0, stream>>>(wq, wk, wv, wo, gw, uw, dw, wsw);
    k_qkv <<<256,  512, 0, stream>>>(x, n1, wsw, q, kbf, vbf);
    dim3 ga(128, 4);
    k_attn<<<ga,   512, 0, stream>>>(q, kbf, vbf, obf);
    k_post<<<256,  512, 0, stream>>>(obf, wsw, anw, x, n2, out);
}